// Round 9
// baseline (496.680 us; speedup 1.0000x reference)
//
#include <hip/hip_runtime.h>
#include <stdint.h>

#define MDIM 16384
#define NDIM 8192
#define KDIM 2048
#define EPS32 1.1920928955078125e-07f
#define BM 256
#define BN 128
#define BK 64

using i32x4 = __attribute__((ext_vector_type(4))) int;
using i32x16 = __attribute__((ext_vector_type(16))) int;
using f32x4 = __attribute__((ext_vector_type(4))) float;
typedef __attribute__((address_space(3))) const int8_t* lds_cptr;

__device__ __forceinline__ void gload_lds16(const void* g, void* l) {
  __builtin_amdgcn_global_load_lds(
      (const __attribute__((address_space(1))) void*)g,
      (__attribute__((address_space(3))) void*)l,
      16, 0, 0);
}

__device__ __forceinline__ uint32_t sgnb(float v) { return (v < 0.f) ? 0xFFu : 0x01u; }

// ---------------------------------------------------------------------------
// Fused pack: blocks [0,MDIM) pack A rows + ab[m]; blocks [MDIM, MDIM+2048)
// pack B transposed tiles + atomicMax column bound.
// ---------------------------------------------------------------------------
__global__ __launch_bounds__(256) void k_pack(const float* __restrict__ x,
                                              const float* __restrict__ W,
                                              int8_t* __restrict__ As,
                                              int8_t* __restrict__ Bs,
                                              float* __restrict__ ab,
                                              unsigned int* __restrict__ wbu) {
  __shared__ char sm[64 * 68];
  __shared__ float red[4][64];
  const int t = threadIdx.x;
  if (blockIdx.x < MDIM) {
    const int m = blockIdx.x;
    const float4* row = (const float4*)(x + (size_t)m * KDIM);
    const float4 v0 = row[2 * t];
    const float4 v1 = row[2 * t + 1];
    const uint32_t p0 = sgnb(v0.x) | (sgnb(v0.y) << 8) | (sgnb(v0.z) << 16) | (sgnb(v0.w) << 24);
    const uint32_t p1 = sgnb(v1.x) | (sgnb(v1.y) << 8) | (sgnb(v1.z) << 16) | (sgnb(v1.w) << 24);
    ((uint2*)(As + (size_t)m * KDIM))[t] = make_uint2(p0, p1);
    float mx = fmaxf(fmaxf(fabsf(v0.x), fabsf(v0.y)), fmaxf(fabsf(v0.z), fabsf(v0.w)));
    mx = fmaxf(mx, fmaxf(fmaxf(fabsf(v1.x), fabsf(v1.y)), fmaxf(fabsf(v1.w), fabsf(v1.z))));
#pragma unroll
    for (int o = 32; o > 0; o >>= 1) mx = fmaxf(mx, __shfl_xor(mx, o, 64));
    if ((t & 63) == 0) red[0][t >> 6] = mx;
    __syncthreads();
    if (t == 0)
      ab[m] = fmaxf(fmaxf(red[0][0], red[0][1]), fmaxf(red[0][2], red[0][3])) + EPS32;
  } else {
    const int bid = blockIdx.x - MDIM;
    const int bd = bid & 31;  // 2048/64 d-tiles
    const int bf = bid >> 5;  // 8192/64 f-tiles
    const int d0 = bd * 64, f0 = bf * 64;
    const int fl = t & 63, dq = t >> 6;
    float mx = 0.f;
#pragma unroll
    for (int i = 0; i < 16; ++i) {
      const int dl = i * 4 + dq;
      const float v = W[(size_t)(d0 + dl) * NDIM + f0 + fl];
      sm[fl * 68 + dl] = (v < 0.f) ? (char)-1 : (char)1;
      mx = fmaxf(mx, fabsf(v));
    }
    red[dq][fl] = mx;
    __syncthreads();
    if (t < 64) {
      const float r = fmaxf(fmaxf(red[0][t], red[1][t]), fmaxf(red[2][t], red[3][t]));
      atomicMax(&wbu[f0 + t], __float_as_uint(r));
    }
    const int nl = t >> 2, ch = t & 3;
    const uint32_t* p = (const uint32_t*)&sm[nl * 68 + ch * 16];
    uint4 o = make_uint4(p[0], p[1], p[2], p[3]);
    *(uint4*)(Bs + (size_t)(f0 + nl) * KDIM + d0 + ch * 16) = o;
  }
}

// ---------------------------------------------------------------------------
// i8 sign-GEMM, 256x128 tile, 8 waves (4x2), per-wave 64x64 (acc[2][2]),
// BK=64, 2-slot LDS ring (48KB total) -> 2 blocks/CU (TLP overlap across
// blocks). Single barrier/iter, lgkmcnt(4/0) ladder, distance-1 prefetch.
// R6's empirically-clean swizzle: phys16Bslot = logical ^ ((row>>3)&3).
// mfma_i32_32x32x32_i8 swapped operands (D rows = n). XCD-chunked remap.
// C[m][n] = 0.25 * ab[m] * (wb[n]+eps) * S + bias[n]
// ---------------------------------------------------------------------------
__global__ __launch_bounds__(512, 4) void k_gemm(const int8_t* __restrict__ As,
                                                 const int8_t* __restrict__ Bs,
                                                 const float* __restrict__ ab,
                                                 const float* __restrict__ wbf,
                                                 const float* __restrict__ bias,
                                                 float* __restrict__ out) {
  __shared__ int8_t lds[2][24576];  // ring slot: A 16KB | B 8KB
  const int t = threadIdx.x;
  const int lane = t & 63, wid = t >> 6;
  // XCD-chunked remap: nwg=4096; per XCD: 8 bm panels, bn in chunks of 8.
  const int bid = blockIdx.x;
  const int xcd = bid & 7;
  const int local = bid >> 3;            // 0..511
  const int bnin = local & 7;
  const int bml = (local >> 3) & 7;
  const int bnc = local >> 6;            // 0..7
  const int bm = xcd * 8 + bml;          // 0..63
  const int bn = bnc * 8 + bnin;         // 0..63
  const size_t m0 = (size_t)bm * BM, n0 = (size_t)bn * BN;
  const int wr = wid >> 1, wc = wid & 1;

  // staging (R6 pattern): dest linear; source slot = (lane&3) ^ xs(row),
  // xs(row) = (row>>3)&3. Each instr = 16 rows x 64B.
  const int r4 = lane >> 2;
  const int sl0 = (lane & 3) ^ ((lane >> 5) & 1);
  const int sl1 = sl0 ^ 2;
  const int slB = (lane & 3) ^ ((2 * wid + ((lane >> 5) & 1)) & 3);
  const int8_t* gA0 = As + (m0 + (size_t)(wid * 32 + r4)) * KDIM + sl0 * 16;
  const int8_t* gA1 = As + (m0 + (size_t)(wid * 32 + 16 + r4)) * KDIM + sl1 * 16;
  const int8_t* gB0 = Bs + (n0 + (size_t)(wid * 16 + r4)) * KDIM + slB * 16;

  // fragment reads: row = base + l31 (+32 via imm 2048), logical slot =
  // kk*2 + h, phys = logical ^ ((l31>>3)&3)  (xs invariant under +32/+64).
  const int l31 = lane & 31, h = lane >> 5;
  const int xs = (l31 >> 3) & 3;
  const int ph0 = (h ^ xs) * 16;
  const int ph1 = ((2 + h) ^ xs) * 16;
  const int aoff0 = (wr * 64 + l31) * 64 + ph0;
  const int aoff1 = (wr * 64 + l31) * 64 + ph1;
  const int boff0 = 16384 + (wc * 64 + l31) * 64 + ph0;
  const int boff1 = 16384 + (wc * 64 + l31) * 64 + ph1;

  i32x16 acc[2][2];
#pragma unroll
  for (int i = 0; i < 2; ++i)
#pragma unroll
    for (int j = 0; j < 2; ++j) acc[i][j] = (i32x16){0};

#define ISSUE(u)                                                  \
  do {                                                            \
    int8_t* base = &lds[(u) & 1][0];                              \
    gload_lds16(gA0 + (size_t)(u) * BK, base + wid * 2048);       \
    gload_lds16(gA1 + (size_t)(u) * BK, base + wid * 2048 + 1024);\
    gload_lds16(gB0 + (size_t)(u) * BK, base + 16384 + wid * 1024);\
  } while (0)

#define DSR(dst, ptr, OFF) \
  asm volatile("ds_read_b128 %0, %1 offset:" #OFF : "=v"(dst) : "v"(ptr))

#define LGK(N)                                              \
  asm volatile("s_waitcnt lgkmcnt(" #N ")" ::: "memory");   \
  __builtin_amdgcn_sched_barrier(0);

// swapped operands: D rows = n (b-frag first), cols = m
#define MFMA4(B0, B1, A0, A1)                                                     \
  acc[0][0] = __builtin_amdgcn_mfma_i32_32x32x32_i8(B0, A0, acc[0][0], 0, 0, 0);  \
  acc[0][1] = __builtin_amdgcn_mfma_i32_32x32x32_i8(B1, A0, acc[0][1], 0, 0, 0);  \
  acc[1][0] = __builtin_amdgcn_mfma_i32_32x32x32_i8(B0, A1, acc[1][0], 0, 0, 0);  \
  acc[1][1] = __builtin_amdgcn_mfma_i32_32x32x32_i8(B1, A1, acc[1][1], 0, 0, 0);

#define ITER(TT, DOISSUE, WAIT_TAIL)                                          \
  {                                                                           \
    const int8_t* sb = &lds[(TT) & 1][0];                                     \
    lds_cptr qa0 = (lds_cptr)(sb + aoff0);                                    \
    lds_cptr qb0 = (lds_cptr)(sb + boff0);                                    \
    lds_cptr qa1 = (lds_cptr)(sb + aoff1);                                    \
    lds_cptr qb1 = (lds_cptr)(sb + boff1);                                    \
    i32x4 a0, a1, a2, a3, b0, b1, b2, b3;                                     \
    if (DOISSUE) ISSUE((TT) + 1);                                             \
    DSR(a0, qa0, 0); DSR(b0, qb0, 0); DSR(a1, qa0, 2048); DSR(b1, qb0, 2048); \
    DSR(a2, qa1, 0); DSR(b2, qb1, 0); DSR(a3, qa1, 2048); DSR(b3, qb1, 2048); \
    LGK(4); __builtin_amdgcn_s_setprio(1);                                    \
    MFMA4(b0, b1, a0, a1);                                                    \
    LGK(0);                                                                   \
    MFMA4(b2, b3, a2, a3);                                                    \
    __builtin_amdgcn_s_setprio(0);                                            \
    asm volatile(WAIT_TAIL ::: "memory");                                     \
    __builtin_amdgcn_s_barrier();                                             \
  }

  // prologue: stage tile 0 into slot 0
  ISSUE(0);
  asm volatile("s_waitcnt vmcnt(0)" ::: "memory");
  __builtin_amdgcn_s_barrier();

#pragma unroll 2
  for (int tt = 0; tt < 30; ++tt) ITER(tt, true, "s_waitcnt vmcnt(0)");
  ITER(30, true, "s_waitcnt vmcnt(0)");
  ITER(31, false, "s_nop 0");

  // epilogue: 32x32 C-map (swapped): m = col = l31, n = (reg&3)+8*(reg>>2)+4*h
#pragma unroll
  for (int i = 0; i < 2; ++i) {
    const size_t m = m0 + wr * 64 + i * 32 + l31;
    const float av = 0.25f * ab[m];
    float* orow = out + m * NDIM;
#pragma unroll
    for (int j = 0; j < 2; ++j) {
#pragma unroll
      for (int q = 0; q < 4; ++q) {
        const size_t nb = n0 + wc * 64 + j * 32 + q * 8 + h * 4;
        const f32x4 wv = *(const f32x4*)&wbf[nb];
        const f32x4 bv = *(const f32x4*)&bias[nb];
        f32x4 o;
        o[0] = av * ((wv[0] + EPS32) * (float)acc[i][j][q * 4 + 0]) + bv[0];
        o[1] = av * ((wv[1] + EPS32) * (float)acc[i][j][q * 4 + 1]) + bv[1];
        o[2] = av * ((wv[2] + EPS32) * (float)acc[i][j][q * 4 + 2]) + bv[2];
        o[3] = av * ((wv[3] + EPS32) * (float)acc[i][j][q * 4 + 3]) + bv[3];
        *(f32x4*)(orow + nb) = o;
      }
    }
  }
#undef ITER
#undef MFMA4
#undef LGK
#undef DSR
#undef ISSUE
}

extern "C" void kernel_launch(void* const* d_in, const int* in_sizes, int n_in,
                              void* d_out, int out_size, void* d_ws, size_t ws_size,
                              hipStream_t stream) {
  const float* x = (const float*)d_in[0];     // (4, 4096, 2048)
  const float* W = (const float*)d_in[1];     // (2048, 8192)
  const float* bias = (const float*)d_in[2];  // (8192,)
  float* out = (float*)d_out;

  char* ws = (char*)d_ws;
  int8_t* As = (int8_t*)ws;                                     // 32 MiB
  int8_t* Bs = (int8_t*)(ws + (size_t)(32u << 20));             // 16 MiB
  float* ab = (float*)(ws + (size_t)(48u << 20));               // 64 KiB
  float* wb = (float*)(ws + (size_t)(48u << 20) + (1u << 16));  // 32 KiB

  (void)hipMemsetAsync(wb, 0, NDIM * sizeof(float), stream);
  k_pack<<<MDIM + (KDIM / 64) * (NDIM / 64), 256, 0, stream>>>(x, W, As, Bs, ab,
                                                               (unsigned int*)wb);
  k_gemm<<<(MDIM / BM) * (NDIM / BN), 512, 0, stream>>>(As, Bs, ab, wb, bias, out);
}

// Round 10
// 475.721 us; speedup vs baseline: 1.0441x; 1.0441x over previous
//
#include <hip/hip_runtime.h>
#include <stdint.h>

#define MDIM 16384
#define NDIM 8192
#define KDIM 2048
#define EPS32 1.1920928955078125e-07f
#define BM 256
#define BN 256
#define BK 64

using i32x4 = __attribute__((ext_vector_type(4))) int;
using i32x16 = __attribute__((ext_vector_type(16))) int;
using f32x4 = __attribute__((ext_vector_type(4))) float;
typedef __attribute__((address_space(3))) const int8_t* lds_cptr;

__device__ __forceinline__ void gload_lds16(const void* g, void* l) {
  __builtin_amdgcn_global_load_lds(
      (const __attribute__((address_space(1))) void*)g,
      (__attribute__((address_space(3))) void*)l,
      16, 0, 0);
}

__device__ __forceinline__ uint32_t sgnb(float v) { return (v < 0.f) ? 0xFFu : 0x01u; }

// ---------------------------------------------------------------------------
// Fused pack: blocks [0,MDIM) pack A rows + ab[m]; blocks [MDIM, MDIM+2048)
// pack B transposed tiles + atomicMax column bound.
// ---------------------------------------------------------------------------
__global__ __launch_bounds__(256) void k_pack(const float* __restrict__ x,
                                              const float* __restrict__ W,
                                              int8_t* __restrict__ As,
                                              int8_t* __restrict__ Bs,
                                              float* __restrict__ ab,
                                              unsigned int* __restrict__ wbu) {
  __shared__ char sm[64 * 68];
  __shared__ float red[4][64];
  const int t = threadIdx.x;
  if (blockIdx.x < MDIM) {
    const int m = blockIdx.x;
    const float4* row = (const float4*)(x + (size_t)m * KDIM);
    const float4 v0 = row[2 * t];
    const float4 v1 = row[2 * t + 1];
    const uint32_t p0 = sgnb(v0.x) | (sgnb(v0.y) << 8) | (sgnb(v0.z) << 16) | (sgnb(v0.w) << 24);
    const uint32_t p1 = sgnb(v1.x) | (sgnb(v1.y) << 8) | (sgnb(v1.z) << 16) | (sgnb(v1.w) << 24);
    ((uint2*)(As + (size_t)m * KDIM))[t] = make_uint2(p0, p1);
    float mx = fmaxf(fmaxf(fabsf(v0.x), fabsf(v0.y)), fmaxf(fabsf(v0.z), fabsf(v0.w)));
    mx = fmaxf(mx, fmaxf(fmaxf(fabsf(v1.x), fabsf(v1.y)), fmaxf(fabsf(v1.w), fabsf(v1.z))));
#pragma unroll
    for (int o = 32; o > 0; o >>= 1) mx = fmaxf(mx, __shfl_xor(mx, o, 64));
    if ((t & 63) == 0) red[0][t >> 6] = mx;
    __syncthreads();
    if (t == 0)
      ab[m] = fmaxf(fmaxf(red[0][0], red[0][1]), fmaxf(red[0][2], red[0][3])) + EPS32;
  } else {
    const int bid = blockIdx.x - MDIM;
    const int bd = bid & 31;  // 2048/64 d-tiles
    const int bf = bid >> 5;  // 8192/64 f-tiles
    const int d0 = bd * 64, f0 = bf * 64;
    const int fl = t & 63, dq = t >> 6;
    float mx = 0.f;
#pragma unroll
    for (int i = 0; i < 16; ++i) {
      const int dl = i * 4 + dq;
      const float v = W[(size_t)(d0 + dl) * NDIM + f0 + fl];
      sm[fl * 68 + dl] = (v < 0.f) ? (char)-1 : (char)1;
      mx = fmaxf(mx, fabsf(v));
    }
    red[dq][fl] = mx;
    __syncthreads();
    if (t < 64) {
      const float r = fmaxf(fmaxf(red[0][t], red[1][t]), fmaxf(red[2][t], red[3][t]));
      atomicMax(&wbu[f0 + t], __float_as_uint(r));
    }
    const int nl = t >> 2, ch = t & 3;
    const uint32_t* p = (const uint32_t*)&sm[nl * 68 + ch * 16];
    uint4 o = make_uint4(p[0], p[1], p[2], p[3]);
    *(uint4*)(Bs + (size_t)(f0 + nl) * KDIM + d0 + ch * 16) = o;
  }
}

// ---------------------------------------------------------------------------
// i8 sign-GEMM, 256x256 tile, 4 waves (2x2), per-wave 128x128 (acc[4][4],
// 256 acc regs -> 1 wave/SIMD, ILP regime: LDS port demand 0.67x MFMA).
// BK=64 (64B rows: only empirically conflict-free layout), 4-slot ring,
// distance-3 counted vmcnt(16), lgkmcnt(8/0) ladder, one barrier/iter.
// mfma_i32_32x32x32_i8 swapped operands (D rows = n). XCD L2-chunked remap.
// C[m][n] = 0.25 * ab[m] * (wb[n]+eps) * S + bias[n]
// ---------------------------------------------------------------------------
__global__ __launch_bounds__(256, 1) void k_gemm(const int8_t* __restrict__ As,
                                                 const int8_t* __restrict__ Bs,
                                                 const float* __restrict__ ab,
                                                 const float* __restrict__ wbf,
                                                 const float* __restrict__ bias,
                                                 float* __restrict__ out) {
  __shared__ int8_t lds[4][32768];  // ring slot: A 16KB | B 16KB
  const int t = threadIdx.x;
  const int lane = t & 63, wid = t >> 6;  // 4 waves
  // XCD L2-chunked remap (R5: FETCH 543->197MB). nwg=2048.
  const int bid = blockIdx.x;
  const int xcd = bid & 7;
  const int local = bid >> 3;            // 0..255
  const int bnin = local & 7;
  const int bml = (local >> 3) & 7;
  const int bnc = local >> 6;            // 0..3
  const int bm = xcd * 8 + bml;          // 0..63
  const int bn = bnc * 8 + bnin;         // 0..31
  const size_t m0 = (size_t)bm * BM, n0 = (size_t)bn * BN;
  const int wr = wid >> 1, wc = wid & 1;

  // staging (R6-clean): dest linear; each instr = 16 rows x 64B; source slot
  // = (lane&3) ^ xs(row), xs = (row>>3)&3. Wave stages rows wid*64+c*16.
  const int r4 = lane >> 2;
  const int sle = (lane & 3) ^ ((lane >> 5) & 1);  // even c
  const int slo = sle ^ 2;                          // odd c
  const int8_t* gA[4];
  const int8_t* gB[4];
#pragma unroll
  for (int c = 0; c < 4; ++c) {
    const int sl = (c & 1) ? slo : sle;
    gA[c] = As + (m0 + (size_t)(wid * 64 + c * 16 + r4)) * KDIM + sl * 16;
    gB[c] = Bs + (n0 + (size_t)(wid * 64 + c * 16 + r4)) * KDIM + sl * 16;
  }

  // fragment reads: row = (wr|wc)*128 + i*32 + l31; phys slot =
  // (kk*2+h) ^ ((l31>>3)&3); row-tile offset i*32 rows = imm i*2048.
  const int l31 = lane & 31, h = lane >> 5;
  const int xs = (l31 >> 3) & 3;
  const int s0 = (h ^ xs) * 16, s1 = ((2 + h) ^ xs) * 16;
  const int aoff0 = wr * 8192 + l31 * 64 + s0;
  const int aoff1 = wr * 8192 + l31 * 64 + s1;
  const int boff0 = 16384 + wc * 8192 + l31 * 64 + s0;
  const int boff1 = 16384 + wc * 8192 + l31 * 64 + s1;

  i32x16 acc[4][4];
#pragma unroll
  for (int i = 0; i < 4; ++i)
#pragma unroll
    for (int j = 0; j < 4; ++j) acc[i][j] = (i32x16){0};

#define ISSUE(u)                                                        \
  do {                                                                  \
    int8_t* base = &lds[(u) & 3][0];                                    \
    _Pragma("unroll") for (int c = 0; c < 4; ++c) {                     \
      gload_lds16(gA[c] + (size_t)(u) * BK, base + wid * 4096 + c * 1024);           \
      gload_lds16(gB[c] + (size_t)(u) * BK, base + 16384 + wid * 4096 + c * 1024);   \
    }                                                                   \
  } while (0)

#define DSR(dst, ptr, OFF) \
  asm volatile("ds_read_b128 %0, %1 offset:" #OFF : "=v"(dst) : "v"(ptr))

#define LGK(N)                                              \
  asm volatile("s_waitcnt lgkmcnt(" #N ")" ::: "memory");   \
  __builtin_amdgcn_sched_barrier(0);

// swapped operands: D rows = n (b-frag first), cols = m
#define MK16(B0, B1, B2, B3, A0, A1, A2, A3)                                      \
  acc[0][0] = __builtin_amdgcn_mfma_i32_32x32x32_i8(B0, A0, acc[0][0], 0, 0, 0);  \
  acc[0][1] = __builtin_amdgcn_mfma_i32_32x32x32_i8(B1, A0, acc[0][1], 0, 0, 0);  \
  acc[1][0] = __builtin_amdgcn_mfma_i32_32x32x32_i8(B0, A1, acc[1][0], 0, 0, 0);  \
  acc[1][1] = __builtin_amdgcn_mfma_i32_32x32x32_i8(B1, A1, acc[1][1], 0, 0, 0);  \
  acc[0][2] = __builtin_amdgcn_mfma_i32_32x32x32_i8(B2, A0, acc[0][2], 0, 0, 0);  \
  acc[0][3] = __builtin_amdgcn_mfma_i32_32x32x32_i8(B3, A0, acc[0][3], 0, 0, 0);  \
  acc[1][2] = __builtin_amdgcn_mfma_i32_32x32x32_i8(B2, A1, acc[1][2], 0, 0, 0);  \
  acc[1][3] = __builtin_amdgcn_mfma_i32_32x32x32_i8(B3, A1, acc[1][3], 0, 0, 0);  \
  acc[2][0] = __builtin_amdgcn_mfma_i32_32x32x32_i8(B0, A2, acc[2][0], 0, 0, 0);  \
  acc[2][1] = __builtin_amdgcn_mfma_i32_32x32x32_i8(B1, A2, acc[2][1], 0, 0, 0);  \
  acc[3][0] = __builtin_amdgcn_mfma_i32_32x32x32_i8(B0, A3, acc[3][0], 0, 0, 0);  \
  acc[3][1] = __builtin_amdgcn_mfma_i32_32x32x32_i8(B1, A3, acc[3][1], 0, 0, 0);  \
  acc[2][2] = __builtin_amdgcn_mfma_i32_32x32x32_i8(B2, A2, acc[2][2], 0, 0, 0);  \
  acc[2][3] = __builtin_amdgcn_mfma_i32_32x32x32_i8(B3, A2, acc[2][3], 0, 0, 0);  \
  acc[3][2] = __builtin_amdgcn_mfma_i32_32x32x32_i8(B2, A3, acc[3][2], 0, 0, 0);  \
  acc[3][3] = __builtin_amdgcn_mfma_i32_32x32x32_i8(B3, A3, acc[3][3], 0, 0, 0);

#define ITER(TT, DOISSUE, WAIT_TAIL)                                          \
  {                                                                           \
    const int8_t* sb = &lds[(TT) & 3][0];                                     \
    lds_cptr pA0 = (lds_cptr)(sb + aoff0);                                    \
    lds_cptr pA1 = (lds_cptr)(sb + aoff1);                                    \
    lds_cptr pB0 = (lds_cptr)(sb + boff0);                                    \
    lds_cptr pB1 = (lds_cptr)(sb + boff1);                                    \
    i32x4 a0, a1, a2, a3, a4, a5, a6, a7;                                     \
    i32x4 b0, b1, b2, b3, b4, b5, b6, b7;                                     \
    if (DOISSUE) ISSUE((TT) + 3);                                             \
    DSR(b0, pB0, 0); DSR(b1, pB0, 2048); DSR(b2, pB0, 4096); DSR(b3, pB0, 6144); \
    DSR(a0, pA0, 0); DSR(a1, pA0, 2048); DSR(a2, pA0, 4096); DSR(a3, pA0, 6144); \
    DSR(b4, pB1, 0); DSR(b5, pB1, 2048); DSR(b6, pB1, 4096); DSR(b7, pB1, 6144); \
    DSR(a4, pA1, 0); DSR(a5, pA1, 2048); DSR(a6, pA1, 4096); DSR(a7, pA1, 6144); \
    LGK(8); __builtin_amdgcn_s_setprio(1);                                    \
    MK16(b0, b1, b2, b3, a0, a1, a2, a3);                                     \
    LGK(0);                                                                   \
    MK16(b4, b5, b6, b7, a4, a5, a6, a7);                                     \
    __builtin_amdgcn_s_setprio(0);                                            \
    asm volatile(WAIT_TAIL ::: "memory");                                     \
    __builtin_amdgcn_s_barrier();                                             \
  }

  // prologue: stage tiles 0,1,2 into ring slots 0,1,2 (8 loads/wave each)
  ISSUE(0); ISSUE(1); ISSUE(2);
  asm volatile("s_waitcnt vmcnt(16)" ::: "memory");  // tile 0 landed
  __builtin_amdgcn_s_barrier();

  for (int tt = 0; tt < 28; ++tt) ITER(tt, true, "s_waitcnt vmcnt(16)");
  ITER(28, true, "s_waitcnt vmcnt(16)");  // issues tile 31
  ITER(29, false, "s_waitcnt vmcnt(8)");
  ITER(30, false, "s_waitcnt vmcnt(0)");
  ITER(31, false, "s_nop 0");

  // epilogue: 32x32 C-map (swapped): m = col = l31, n = (reg&3)+8*(reg>>2)+4*h
#pragma unroll
  for (int i = 0; i < 4; ++i) {
    const size_t m = m0 + wr * 128 + i * 32 + l31;
    const float av = 0.25f * ab[m];
    float* orow = out + m * NDIM;
#pragma unroll
    for (int j = 0; j < 4; ++j) {
#pragma unroll
      for (int q = 0; q < 4; ++q) {
        const size_t nb = n0 + wc * 128 + j * 32 + q * 8 + h * 4;
        const f32x4 wv = *(const f32x4*)&wbf[nb];
        const f32x4 bv = *(const f32x4*)&bias[nb];
        f32x4 o;
        o[0] = av * ((wv[0] + EPS32) * (float)acc[i][j][q * 4 + 0]) + bv[0];
        o[1] = av * ((wv[1] + EPS32) * (float)acc[i][j][q * 4 + 1]) + bv[1];
        o[2] = av * ((wv[2] + EPS32) * (float)acc[i][j][q * 4 + 2]) + bv[2];
        o[3] = av * ((wv[3] + EPS32) * (float)acc[i][j][q * 4 + 3]) + bv[3];
        *(f32x4*)(orow + nb) = o;
      }
    }
  }
#undef ITER
#undef MK16
#undef LGK
#undef DSR
#undef ISSUE
}

extern "C" void kernel_launch(void* const* d_in, const int* in_sizes, int n_in,
                              void* d_out, int out_size, void* d_ws, size_t ws_size,
                              hipStream_t stream) {
  const float* x = (const float*)d_in[0];     // (4, 4096, 2048)
  const float* W = (const float*)d_in[1];     // (2048, 8192)
  const float* bias = (const float*)d_in[2];  // (8192,)
  float* out = (float*)d_out;

  char* ws = (char*)d_ws;
  int8_t* As = (int8_t*)ws;                                     // 32 MiB
  int8_t* Bs = (int8_t*)(ws + (size_t)(32u << 20));             // 16 MiB
  float* ab = (float*)(ws + (size_t)(48u << 20));               // 64 KiB
  float* wb = (float*)(ws + (size_t)(48u << 20) + (1u << 16));  // 32 KiB

  (void)hipMemsetAsync(wb, 0, NDIM * sizeof(float), stream);
  k_pack<<<MDIM + (KDIM / 64) * (NDIM / 64), 256, 0, stream>>>(x, W, As, Bs, ab,
                                                               (unsigned int*)wb);
  k_gemm<<<(MDIM / BM) * (NDIM / BN), 256, 0, stream>>>(As, Bs, ab, wb, bias, out);
}

// Round 11
// 308.432 us; speedup vs baseline: 1.6103x; 1.5424x over previous
//
#include <hip/hip_runtime.h>
#include <stdint.h>

#define MDIM 16384
#define NDIM 8192
#define KDIM 2048
#define KB2 1024  // packed fp4 row bytes (KDIM/2)
#define EPS32 1.1920928955078125e-07f
#define BM 256
#define BN 256
// BK = 128 fp4 elements = 64 bytes per row per K-tile

using i32x4 = __attribute__((ext_vector_type(4))) int;
using i32x8 = __attribute__((ext_vector_type(8))) int;
using f32x4 = __attribute__((ext_vector_type(4))) float;
using f32x16 = __attribute__((ext_vector_type(16))) float;
typedef __attribute__((address_space(3))) const int8_t* lds_cptr;

__device__ __forceinline__ void gload_lds16(const void* g, void* l) {
  __builtin_amdgcn_global_load_lds(
      (const __attribute__((address_space(1))) void*)g,
      (__attribute__((address_space(3))) void*)l,
      16, 0, 0);
}

// fp4 E2M1 nibble: +1.0 = 0x2, -1.0 = 0xA
__device__ __forceinline__ uint32_t nib(float v) { return (v < 0.f) ? 0xAu : 0x2u; }

// ---------------------------------------------------------------------------
// Fused pack (fp4): blocks [0,MDIM) pack A rows + ab[m]; blocks
// [MDIM, MDIM+2048) pack B transposed + atomicMax column bound.
// ---------------------------------------------------------------------------
__global__ __launch_bounds__(256) void k_pack(const float* __restrict__ x,
                                              const float* __restrict__ W,
                                              uint8_t* __restrict__ As,
                                              uint8_t* __restrict__ Bs,
                                              float* __restrict__ ab,
                                              unsigned int* __restrict__ wbu) {
  __shared__ uint8_t sm[64 * 68];
  __shared__ float red[4][64];
  const int t = threadIdx.x;
  if (blockIdx.x < MDIM) {
    const int m = blockIdx.x;
    const float4* row = (const float4*)(x + (size_t)m * KDIM);
    const float4 v0 = row[2 * t];
    const float4 v1 = row[2 * t + 1];
    const uint32_t pk =
        nib(v0.x) | (nib(v0.y) << 4) | (nib(v0.z) << 8) | (nib(v0.w) << 12) |
        (nib(v1.x) << 16) | (nib(v1.y) << 20) | (nib(v1.z) << 24) | (nib(v1.w) << 28);
    ((uint32_t*)(As + (size_t)m * KB2))[t] = pk;
    float mx = fmaxf(fmaxf(fabsf(v0.x), fabsf(v0.y)), fmaxf(fabsf(v0.z), fabsf(v0.w)));
    mx = fmaxf(mx, fmaxf(fmaxf(fabsf(v1.x), fabsf(v1.y)), fmaxf(fabsf(v1.z), fabsf(v1.w))));
#pragma unroll
    for (int o = 32; o > 0; o >>= 1) mx = fmaxf(mx, __shfl_xor(mx, o, 64));
    if ((t & 63) == 0) red[0][t >> 6] = mx;
    __syncthreads();
    if (t == 0)
      ab[m] = fmaxf(fmaxf(red[0][0], red[0][1]), fmaxf(red[0][2], red[0][3])) + EPS32;
  } else {
    const int bid = blockIdx.x - MDIM;
    const int bd = bid & 31;  // 2048/64 d-tiles
    const int bf = bid >> 5;  // 8192/64 f-tiles
    const int d0 = bd * 64, f0 = bf * 64;
    const int fl = t & 63, dq = t >> 6;
    float mx = 0.f;
#pragma unroll
    for (int i = 0; i < 16; ++i) {
      const int dl = i * 4 + dq;
      const float v = W[(size_t)(d0 + dl) * NDIM + f0 + fl];
      sm[fl * 68 + dl] = (uint8_t)nib(v);
      mx = fmaxf(mx, fabsf(v));
    }
    red[dq][fl] = mx;
    __syncthreads();
    if (t < 64) {
      const float r = fmaxf(fmaxf(red[0][t], red[1][t]), fmaxf(red[2][t], red[3][t]));
      atomicMax(&wbu[f0 + t], __float_as_uint(r));
    }
    // writer: 64 f-rows x 32 packed bytes; thread = (row nl, 16-d chunk ch)
    const int nl = t >> 2, ch = t & 3;
    const uint8_t* s = &sm[nl * 68 + ch * 16];
    uint32_t w0 = 0, w1 = 0;
#pragma unroll
    for (int i = 0; i < 4; ++i)
      w0 |= (uint32_t)(s[2 * i] | (s[2 * i + 1] << 4)) << (8 * i);
#pragma unroll
    for (int i = 0; i < 4; ++i)
      w1 |= (uint32_t)(s[8 + 2 * i] | (s[9 + 2 * i] << 4)) << (8 * i);
    *(uint2*)(Bs + (size_t)(f0 + nl) * KB2 + (d0 >> 1) + ch * 8) = make_uint2(w0, w1);
  }
}

// ---------------------------------------------------------------------------
// MX-FP4 sign-GEMM: 256x256 tile, 8 waves (2x4), K-tile = 128 elems (64B
// rows), 4-slot LDS ring, distance-3 counted vmcnt, single barrier/iter,
// counted-lgkmcnt ladder. mfma_scale_f32_32x32x64_f8f6f4 (fmt fp4, unity
// scales), swapped operands (D rows = n). R6's conflict-free swizzle:
// phys16Bslot = logical ^ ((row>>3)&3). XCD L2-chunked remap.
// C[m][n] = 0.25 * ab[m] * (wb[n]+eps) * S + bias[n]
// ---------------------------------------------------------------------------
__global__ __launch_bounds__(512, 2) void k_gemm(const uint8_t* __restrict__ As,
                                                 const uint8_t* __restrict__ Bs,
                                                 const float* __restrict__ ab,
                                                 const float* __restrict__ wbf,
                                                 const float* __restrict__ bias,
                                                 float* __restrict__ out) {
  __shared__ int8_t lds[4][32768];  // ring slot: A 16KB | B 16KB
  const int t = threadIdx.x;
  const int lane = t & 63, wid = t >> 6;
  // XCD L2-chunked remap (R5: FETCH 543->197MB). nwg=2048.
  const int bid = blockIdx.x;
  const int xcd = bid & 7;
  const int local = bid >> 3;
  const int bnin = local & 7;
  const int bml = (local >> 3) & 7;
  const int bnc = local >> 6;
  const int bm = xcd * 8 + bml;
  const int bn = bnc * 8 + bnin;
  const size_t m0 = (size_t)bm * BM, n0 = (size_t)bn * BN;
  const int wr = wid >> 2, wc = wid & 3;

  // staging (R6-clean): dest linear; instr = 16 rows x 64B; source slot =
  // (lane&3) ^ xs(row), xs = (row>>3)&3.
  const int r4 = lane >> 2;
  const int sl0 = (lane & 3) ^ ((lane >> 5) & 1);
  const int sl1 = sl0 ^ 2;
  const uint8_t* gA0 = As + (m0 + (size_t)(wid * 32 + r4)) * KB2 + sl0 * 16;
  const uint8_t* gA1 = As + (m0 + (size_t)(wid * 32 + 16 + r4)) * KB2 + sl1 * 16;
  const uint8_t* gB0 = Bs + (n0 + (size_t)(wid * 32 + r4)) * KB2 + sl0 * 16;
  const uint8_t* gB1 = Bs + (n0 + (size_t)(wid * 32 + 16 + r4)) * KB2 + sl1 * 16;

  // fragment reads: row = l31 (+32 per i via imm 2048), logical slot =
  // kk*2 + h, phys = logical ^ ((l31>>3)&3).
  const int l31 = lane & 31, h = lane >> 5;
  const int xs = (l31 >> 3) & 3;
  const int aoff0 = (wr * 128 + l31) * 64 + ((h ^ xs) * 16);
  const int aoff1 = (wr * 128 + l31) * 64 + (((2 + h) ^ xs) * 16);
  const int boff0 = 16384 + (wc * 64 + l31) * 64 + ((h ^ xs) * 16);
  const int boff1 = 16384 + (wc * 64 + l31) * 64 + (((2 + h) ^ xs) * 16);

  f32x16 acc[4][2];
#pragma unroll
  for (int i = 0; i < 4; ++i)
#pragma unroll
    for (int j = 0; j < 2; ++j) acc[i][j] = (f32x16){0};

#define ISSUE_A(u)                                      \
  do {                                                  \
    int8_t* dA = &lds[(u) & 3][wid * 2048];             \
    gload_lds16(gA0 + (size_t)(u) * 64, dA);            \
    gload_lds16(gA1 + (size_t)(u) * 64, dA + 1024);     \
  } while (0)
#define ISSUE_B(u)                                      \
  do {                                                  \
    int8_t* dB = &lds[(u) & 3][16384 + wid * 2048];     \
    gload_lds16(gB0 + (size_t)(u) * 64, dB);            \
    gload_lds16(gB1 + (size_t)(u) * 64, dB + 1024);     \
  } while (0)

#define DSR(dst, ptr, OFF) \
  asm volatile("ds_read_b128 %0, %1 offset:" #OFF : "=v"(dst) : "v"(ptr))

#define FRAG(x) __builtin_shufflevector((x), (x), 0, 1, 2, 3, -1, -1, -1, -1)

// swapped operands: D rows = n (b-frag first), cols = m. fmt 4/4 = fp4,
// scales = E8M0 0x7F (1.0).
#define SMFMA(D, BF, AF)                                                     \
  D = __builtin_amdgcn_mfma_scale_f32_32x32x64_f8f6f4(                       \
      FRAG(BF), FRAG(AF), D, 4, 4, 0, 0x7F7F7F7F, 0, 0x7F7F7F7F)

#define MP(I, B0, B1, AF) SMFMA(acc[I][0], B0, AF); SMFMA(acc[I][1], B1, AF)

#define LGK(N)                                              \
  asm volatile("s_waitcnt lgkmcnt(" #N ")" ::: "memory");   \
  __builtin_amdgcn_sched_barrier(0);

#define ITER(TT, DOISSUE, WAIT_TAIL)                                          \
  {                                                                           \
    const int8_t* sb = &lds[(TT) & 3][0];                                     \
    lds_cptr pA0 = (lds_cptr)(sb + aoff0);                                    \
    lds_cptr pA1 = (lds_cptr)(sb + aoff1);                                    \
    lds_cptr pB0 = (lds_cptr)(sb + boff0);                                    \
    lds_cptr pB1 = (lds_cptr)(sb + boff1);                                    \
    i32x4 a0, a1, a2, a3, a4, a5, a6, a7, b0, b1, b2, b3;                     \
    if (DOISSUE) { ISSUE_A((TT) + 3); ISSUE_B((TT) + 3); }                    \
    DSR(a0, pA0, 0); DSR(b0, pB0, 0); DSR(b1, pB0, 2048);                     \
    DSR(a1, pA0, 2048); DSR(a2, pA0, 4096); DSR(a3, pA0, 6144);               \
    DSR(a4, pA1, 0); DSR(b2, pB1, 0); DSR(b3, pB1, 2048);                     \
    DSR(a5, pA1, 2048); DSR(a6, pA1, 4096); DSR(a7, pA1, 6144);               \
    LGK(9); __builtin_amdgcn_s_setprio(1); MP(0, b0, b1, a0);                 \
    LGK(8); MP(1, b0, b1, a1);                                                \
    LGK(7); MP(2, b0, b1, a2);                                                \
    LGK(6); MP(3, b0, b1, a3);                                                \
    LGK(3); MP(0, b2, b3, a4);                                                \
    LGK(2); MP(1, b2, b3, a5);                                                \
    LGK(1); MP(2, b2, b3, a6);                                                \
    LGK(0); MP(3, b2, b3, a7);                                                \
    __builtin_amdgcn_s_setprio(0);                                            \
    asm volatile(WAIT_TAIL ::: "memory");                                     \
    __builtin_amdgcn_s_barrier();                                             \
  }

  // prologue: stage tiles 0,1,2 into ring slots 0,1,2 (4 loads/wave/tile)
  ISSUE_A(0); ISSUE_B(0);
  ISSUE_A(1); ISSUE_B(1);
  ISSUE_A(2); ISSUE_B(2);
  asm volatile("s_waitcnt vmcnt(8)" ::: "memory");  // tile 0 landed
  __builtin_amdgcn_s_barrier();

#pragma unroll 2
  for (int tt = 0; tt < 12; ++tt) ITER(tt, true, "s_waitcnt vmcnt(8)");
  ITER(12, true, "s_waitcnt vmcnt(8)");   // issues tile 15
  ITER(13, false, "s_waitcnt vmcnt(4)");
  ITER(14, false, "s_waitcnt vmcnt(0)");
  ITER(15, false, "s_nop 0");

  // epilogue: 32x32 C-map (swapped): m = col = l31, n = (reg&3)+8*(reg>>2)+4*h
#pragma unroll
  for (int i = 0; i < 4; ++i) {
    const size_t m = m0 + wr * 128 + i * 32 + l31;
    const float av = 0.25f * ab[m];
    float* orow = out + m * NDIM;
#pragma unroll
    for (int j = 0; j < 2; ++j) {
#pragma unroll
      for (int q = 0; q < 4; ++q) {
        const size_t nb = n0 + wc * 64 + j * 32 + q * 8 + h * 4;
        const f32x4 wv = *(const f32x4*)&wbf[nb];
        const f32x4 bv = *(const f32x4*)&bias[nb];
        f32x4 o;
        o[0] = av * ((wv[0] + EPS32) * acc[i][j][q * 4 + 0]) + bv[0];
        o[1] = av * ((wv[1] + EPS32) * acc[i][j][q * 4 + 1]) + bv[1];
        o[2] = av * ((wv[2] + EPS32) * acc[i][j][q * 4 + 2]) + bv[2];
        o[3] = av * ((wv[3] + EPS32) * acc[i][j][q * 4 + 3]) + bv[3];
        *(f32x4*)(orow + nb) = o;
      }
    }
  }
#undef ITER
#undef LGK
#undef MP
#undef SMFMA
#undef FRAG
#undef DSR
#undef ISSUE_A
#undef ISSUE_B
}

extern "C" void kernel_launch(void* const* d_in, const int* in_sizes, int n_in,
                              void* d_out, int out_size, void* d_ws, size_t ws_size,
                              hipStream_t stream) {
  const float* x = (const float*)d_in[0];     // (4, 4096, 2048)
  const float* W = (const float*)d_in[1];     // (2048, 8192)
  const float* bias = (const float*)d_in[2];  // (8192,)
  float* out = (float*)d_out;

  char* ws = (char*)d_ws;
  uint8_t* As = (uint8_t*)ws;                                   // 16 MiB fp4
  uint8_t* Bs = (uint8_t*)(ws + (size_t)(16u << 20));           // 8 MiB fp4
  float* ab = (float*)(ws + (size_t)(24u << 20));               // 64 KiB
  float* wb = (float*)(ws + (size_t)(24u << 20) + (1u << 16));  // 32 KiB

  (void)hipMemsetAsync(wb, 0, NDIM * sizeof(float), stream);
  k_pack<<<MDIM + (KDIM / 64) * (NDIM / 64), 256, 0, stream>>>(x, W, As, Bs, ab,
                                                               (unsigned int*)wb);
  k_gemm<<<(MDIM / BM) * (NDIM / BN), 512, 0, stream>>>(As, Bs, ab, wb, bias, out);
}

// Round 12
// 307.127 us; speedup vs baseline: 1.6172x; 1.0042x over previous
//
#include <hip/hip_runtime.h>
#include <stdint.h>

#define MDIM 16384
#define NDIM 8192
#define KDIM 2048
#define KB2 1024  // packed fp4 row bytes (KDIM/2)
#define EPS32 1.1920928955078125e-07f
#define BM 256
#define BN 256
// K-tile = 128 fp4 elements = 64 bytes per row

using i32x4 = __attribute__((ext_vector_type(4))) int;
using f32x4 = __attribute__((ext_vector_type(4))) float;
using f32x16 = __attribute__((ext_vector_type(16))) float;
typedef __attribute__((address_space(3))) const int8_t* lds_cptr;

__device__ __forceinline__ void gload_lds16(const void* g, void* l) {
  __builtin_amdgcn_global_load_lds(
      (const __attribute__((address_space(1))) void*)g,
      (__attribute__((address_space(3))) void*)l,
      16, 0, 0);
}

// fp4 E2M1 nibble: +1.0 = 0x2, -1.0 = 0xA
__device__ __forceinline__ uint32_t nib(float v) { return (v < 0.f) ? 0xAu : 0x2u; }

// ---------------------------------------------------------------------------
// Fused pack (fp4): blocks [0,MDIM) pack A rows + ab[m]; blocks
// [MDIM, MDIM+2048) pack B transposed + atomicMax column bound.
// ---------------------------------------------------------------------------
__global__ __launch_bounds__(256) void k_pack(const float* __restrict__ x,
                                              const float* __restrict__ W,
                                              uint8_t* __restrict__ As,
                                              uint8_t* __restrict__ Bs,
                                              float* __restrict__ ab,
                                              unsigned int* __restrict__ wbu) {
  __shared__ uint8_t sm[64 * 68];
  __shared__ float red[4][64];
  const int t = threadIdx.x;
  if (blockIdx.x < MDIM) {
    const int m = blockIdx.x;
    const float4* row = (const float4*)(x + (size_t)m * KDIM);
    const float4 v0 = row[2 * t];
    const float4 v1 = row[2 * t + 1];
    const uint32_t pk =
        nib(v0.x) | (nib(v0.y) << 4) | (nib(v0.z) << 8) | (nib(v0.w) << 12) |
        (nib(v1.x) << 16) | (nib(v1.y) << 20) | (nib(v1.z) << 24) | (nib(v1.w) << 28);
    ((uint32_t*)(As + (size_t)m * KB2))[t] = pk;
    float mx = fmaxf(fmaxf(fabsf(v0.x), fabsf(v0.y)), fmaxf(fabsf(v0.z), fabsf(v0.w)));
    mx = fmaxf(mx, fmaxf(fmaxf(fabsf(v1.x), fabsf(v1.y)), fmaxf(fabsf(v1.z), fabsf(v1.w))));
#pragma unroll
    for (int o = 32; o > 0; o >>= 1) mx = fmaxf(mx, __shfl_xor(mx, o, 64));
    if ((t & 63) == 0) red[0][t >> 6] = mx;
    __syncthreads();
    if (t == 0)
      ab[m] = fmaxf(fmaxf(red[0][0], red[0][1]), fmaxf(red[0][2], red[0][3])) + EPS32;
  } else {
    const int bid = blockIdx.x - MDIM;
    const int bd = bid & 31;  // 2048/64 d-tiles
    const int bf = bid >> 5;  // 8192/64 f-tiles
    const int d0 = bd * 64, f0 = bf * 64;
    const int fl = t & 63, dq = t >> 6;
    float mx = 0.f;
#pragma unroll
    for (int i = 0; i < 16; ++i) {
      const int dl = i * 4 + dq;
      const float v = W[(size_t)(d0 + dl) * NDIM + f0 + fl];
      sm[fl * 68 + dl] = (uint8_t)nib(v);
      mx = fmaxf(mx, fabsf(v));
    }
    red[dq][fl] = mx;
    __syncthreads();
    if (t < 64) {
      const float r = fmaxf(fmaxf(red[0][t], red[1][t]), fmaxf(red[2][t], red[3][t]));
      atomicMax(&wbu[f0 + t], __float_as_uint(r));
    }
    // writer: 64 f-rows x 32 packed bytes; thread = (row nl, 16-d chunk ch)
    const int nl = t >> 2, ch = t & 3;
    const uint8_t* s = &sm[nl * 68 + ch * 16];
    uint32_t w0 = 0, w1 = 0;
#pragma unroll
    for (int i = 0; i < 4; ++i)
      w0 |= (uint32_t)(s[2 * i] | (s[2 * i + 1] << 4)) << (8 * i);
#pragma unroll
    for (int i = 0; i < 4; ++i)
      w1 |= (uint32_t)(s[8 + 2 * i] | (s[9 + 2 * i] << 4)) << (8 * i);
    *(uint2*)(Bs + (size_t)(f0 + nl) * KB2 + (d0 >> 1) + ch * 8) = make_uint2(w0, w1);
  }
}

// ---------------------------------------------------------------------------
// MX-FP4 sign-GEMM, register-bank pipelined: 256x256 tile, 8 waves (2x4),
// K-tile = 128 elems (64B rows), 4-slot LDS ring, distance-3 prefetch.
// Per iter: {lgkm(0); vmcnt(4); barrier; ISSUE(N+3); READS(N+1)->bank;
// MFMA(N) from other bank, ZERO internal waits}. Reads(N+1) drain under
// MFMA(N). R6 conflict-free swizzle: phys16Bslot = logical ^ ((row>>3)&3).
// C[m][n] = 0.25 * ab[m] * (wb[n]+eps) * S + bias[n]
// ---------------------------------------------------------------------------
__global__ __launch_bounds__(512, 2) void k_gemm(const uint8_t* __restrict__ As,
                                                 const uint8_t* __restrict__ Bs,
                                                 const float* __restrict__ ab,
                                                 const float* __restrict__ wbf,
                                                 const float* __restrict__ bias,
                                                 float* __restrict__ out) {
  __shared__ int8_t lds[4][32768];  // ring slot: A 16KB | B 16KB
  const int t = threadIdx.x;
  const int lane = t & 63, wid = t >> 6;
  // XCD L2-chunked remap (R5: FETCH 543->197MB). nwg=2048.
  const int bid = blockIdx.x;
  const int xcd = bid & 7;
  const int local = bid >> 3;
  const int bnin = local & 7;
  const int bml = (local >> 3) & 7;
  const int bnc = local >> 6;
  const int bm = xcd * 8 + bml;
  const int bn = bnc * 8 + bnin;
  const size_t m0 = (size_t)bm * BM, n0 = (size_t)bn * BN;
  const int wr = wid >> 2, wc = wid & 3;

  // staging (R6-clean): dest linear; instr = 16 rows x 64B; source slot =
  // (lane&3) ^ xs(row), xs = (row>>3)&3.
  const int r4 = lane >> 2;
  const int sl0 = (lane & 3) ^ ((lane >> 5) & 1);
  const int sl1 = sl0 ^ 2;
  const uint8_t* gA0 = As + (m0 + (size_t)(wid * 32 + r4)) * KB2 + sl0 * 16;
  const uint8_t* gA1 = As + (m0 + (size_t)(wid * 32 + 16 + r4)) * KB2 + sl1 * 16;
  const uint8_t* gB0 = Bs + (n0 + (size_t)(wid * 32 + r4)) * KB2 + sl0 * 16;
  const uint8_t* gB1 = Bs + (n0 + (size_t)(wid * 32 + 16 + r4)) * KB2 + sl1 * 16;

  // fragment reads: row = l31 (+32 per i via imm 2048), logical slot =
  // kk*2 + h, phys = logical ^ ((l31>>3)&3).
  const int l31 = lane & 31, h = lane >> 5;
  const int xs = (l31 >> 3) & 3;
  const int aoff0 = (wr * 128 + l31) * 64 + ((h ^ xs) * 16);
  const int aoff1 = (wr * 128 + l31) * 64 + (((2 + h) ^ xs) * 16);
  const int boff0 = 16384 + (wc * 64 + l31) * 64 + ((h ^ xs) * 16);
  const int boff1 = 16384 + (wc * 64 + l31) * 64 + (((2 + h) ^ xs) * 16);

  f32x16 acc[4][2];
#pragma unroll
  for (int i = 0; i < 4; ++i)
#pragma unroll
    for (int j = 0; j < 2; ++j) acc[i][j] = (f32x16){0};

  // two fragment banks (E/O) for the cross-barrier register pipeline
  i32x4 ea0, ea1, ea2, ea3, ea4, ea5, ea6, ea7, eb0, eb1, eb2, eb3;
  i32x4 oa0, oa1, oa2, oa3, oa4, oa5, oa6, oa7, ob0, ob1, ob2, ob3;

#define ISSUE(u)                                        \
  do {                                                  \
    int8_t* dA = &lds[(u) & 3][wid * 2048];             \
    int8_t* dB = &lds[(u) & 3][16384 + wid * 2048];     \
    gload_lds16(gA0 + (size_t)(u) * 64, dA);            \
    gload_lds16(gA1 + (size_t)(u) * 64, dA + 1024);     \
    gload_lds16(gB0 + (size_t)(u) * 64, dB);            \
    gload_lds16(gB1 + (size_t)(u) * 64, dB + 1024);     \
  } while (0)

#define DSR(dst, ptr, OFF) \
  asm volatile("ds_read_b128 %0, %1 offset:" #OFF : "=v"(dst) : "v"(ptr))

#define READS(SLOT, A0, A1, A2, A3, A4, A5, A6, A7, B0, B1, B2, B3)           \
  {                                                                           \
    const int8_t* sb = &lds[(SLOT)][0];                                       \
    lds_cptr pA0 = (lds_cptr)(sb + aoff0);                                    \
    lds_cptr pA1 = (lds_cptr)(sb + aoff1);                                    \
    lds_cptr pB0 = (lds_cptr)(sb + boff0);                                    \
    lds_cptr pB1 = (lds_cptr)(sb + boff1);                                    \
    DSR(A0, pA0, 0); DSR(B0, pB0, 0); DSR(B1, pB0, 2048);                     \
    DSR(A1, pA0, 2048); DSR(A2, pA0, 4096); DSR(A3, pA0, 6144);               \
    DSR(A4, pA1, 0); DSR(B2, pB1, 0); DSR(B3, pB1, 2048);                     \
    DSR(A5, pA1, 2048); DSR(A6, pA1, 4096); DSR(A7, pA1, 6144);               \
  }

#define FRAG(x) __builtin_shufflevector((x), (x), 0, 1, 2, 3, -1, -1, -1, -1)

// swapped operands: D rows = n (b-frag first). fmt 4/4 = fp4, scales = 1.0.
#define SMFMA(D, BF, AF)                                                      \
  D = __builtin_amdgcn_mfma_scale_f32_32x32x64_f8f6f4(                        \
      FRAG(BF), FRAG(AF), D, 4, 4, 0, 0x7F7F7F7F, 0, 0x7F7F7F7F)

#define MFMAS(A0, A1, A2, A3, A4, A5, A6, A7, B0, B1, B2, B3)                 \
  SMFMA(acc[0][0], B0, A0); SMFMA(acc[0][1], B1, A0);                         \
  SMFMA(acc[1][0], B0, A1); SMFMA(acc[1][1], B1, A1);                         \
  SMFMA(acc[2][0], B0, A2); SMFMA(acc[2][1], B1, A2);                         \
  SMFMA(acc[3][0], B0, A3); SMFMA(acc[3][1], B1, A3);                         \
  SMFMA(acc[0][0], B2, A4); SMFMA(acc[0][1], B3, A4);                         \
  SMFMA(acc[1][0], B2, A5); SMFMA(acc[1][1], B3, A5);                         \
  SMFMA(acc[2][0], B2, A6); SMFMA(acc[2][1], B3, A6);                         \
  SMFMA(acc[3][0], B2, A7); SMFMA(acc[3][1], B3, A7);

#define HEAD(VM)                                                  \
  asm volatile("s_waitcnt lgkmcnt(0)" ::: "memory");              \
  asm volatile("s_waitcnt vmcnt(" #VM ")" ::: "memory");          \
  __builtin_amdgcn_sched_barrier(0);                              \
  __builtin_amdgcn_s_barrier();

// iter with MFMA from E bank, reads into O bank
#define ITER_E(TT, DOISSUE, DOREAD, VM)                                       \
  {                                                                           \
    HEAD(VM);                                                                 \
    if (DOISSUE) ISSUE((TT) + 3);                                             \
    if (DOREAD)                                                               \
      READS(((TT) + 1) & 3, oa0, oa1, oa2, oa3, oa4, oa5, oa6, oa7,           \
            ob0, ob1, ob2, ob3);                                              \
    __builtin_amdgcn_s_setprio(1);                                            \
    MFMAS(ea0, ea1, ea2, ea3, ea4, ea5, ea6, ea7, eb0, eb1, eb2, eb3);        \
    __builtin_amdgcn_s_setprio(0);                                            \
  }
#define ITER_O(TT, DOISSUE, DOREAD, VM)                                       \
  {                                                                           \
    HEAD(VM);                                                                 \
    if (DOISSUE) ISSUE((TT) + 3);                                             \
    if (DOREAD)                                                               \
      READS(((TT) + 1) & 3, ea0, ea1, ea2, ea3, ea4, ea5, ea6, ea7,           \
            eb0, eb1, eb2, eb3);                                              \
    __builtin_amdgcn_s_setprio(1);                                            \
    MFMAS(oa0, oa1, oa2, oa3, oa4, oa5, oa6, oa7, ob0, ob1, ob2, ob3);        \
    __builtin_amdgcn_s_setprio(0);                                            \
  }

  // prologue: stage tiles 0,1,2; confirm tile 0 everywhere; preload bank E
  ISSUE(0); ISSUE(1); ISSUE(2);
  asm volatile("s_waitcnt vmcnt(8)" ::: "memory");
  __builtin_amdgcn_s_barrier();
  READS(0, ea0, ea1, ea2, ea3, ea4, ea5, ea6, ea7, eb0, eb1, eb2, eb3);

  for (int tt = 0; tt < 12; tt += 2) {
    ITER_E(tt, 1, 1, 4);
    ITER_O(tt + 1, 1, 1, 4);
  }
  ITER_E(12, 1, 1, 4);   // issues tile 15, reads tile 13
  ITER_O(13, 0, 1, 4);   // reads tile 14
  ITER_E(14, 0, 1, 0);   // reads tile 15
  ITER_O(15, 0, 0, 0);   // final MFMA

  // epilogue: 32x32 C-map (swapped): m = col = l31, n = (reg&3)+8*(reg>>2)+4*h
#pragma unroll
  for (int i = 0; i < 4; ++i) {
    const size_t m = m0 + wr * 128 + i * 32 + l31;
    const float av = 0.25f * ab[m];
    float* orow = out + m * NDIM;
#pragma unroll
    for (int j = 0; j < 2; ++j) {
#pragma unroll
      for (int q = 0; q < 4; ++q) {
        const size_t nb = n0 + wc * 64 + j * 32 + q * 8 + h * 4;
        const f32x4 wv = *(const f32x4*)&wbf[nb];
        const f32x4 bv = *(const f32x4*)&bias[nb];
        f32x4 o;
        o[0] = av * ((wv[0] + EPS32) * acc[i][j][q * 4 + 0]) + bv[0];
        o[1] = av * ((wv[1] + EPS32) * acc[i][j][q * 4 + 1]) + bv[1];
        o[2] = av * ((wv[2] + EPS32) * acc[i][j][q * 4 + 2]) + bv[2];
        o[3] = av * ((wv[3] + EPS32) * acc[i][j][q * 4 + 3]) + bv[3];
        *(f32x4*)(orow + nb) = o;
      }
    }
  }
#undef ITER_E
#undef ITER_O
#undef HEAD
#undef MFMAS
#undef SMFMA
#undef FRAG
#undef READS
#undef DSR
#undef ISSUE
}

extern "C" void kernel_launch(void* const* d_in, const int* in_sizes, int n_in,
                              void* d_out, int out_size, void* d_ws, size_t ws_size,
                              hipStream_t stream) {
  const float* x = (const float*)d_in[0];     // (4, 4096, 2048)
  const float* W = (const float*)d_in[1];     // (2048, 8192)
  const float* bias = (const float*)d_in[2];  // (8192,)
  float* out = (float*)d_out;

  char* ws = (char*)d_ws;
  uint8_t* As = (uint8_t*)ws;                                   // 16 MiB fp4
  uint8_t* Bs = (uint8_t*)(ws + (size_t)(16u << 20));           // 8 MiB fp4
  float* ab = (float*)(ws + (size_t)(24u << 20));               // 64 KiB
  float* wb = (float*)(ws + (size_t)(24u << 20) + (1u << 16));  // 32 KiB

  (void)hipMemsetAsync(wb, 0, NDIM * sizeof(float), stream);
  k_pack<<<MDIM + (KDIM / 64) * (NDIM / 64), 256, 0, stream>>>(x, W, As, Bs, ab,
                                                               (unsigned int*)wb);
  k_gemm<<<(MDIM / BM) * (NDIM / BN), 512, 0, stream>>>(As, Bs, ab, wb, bias, out);
}

// Round 13
// 302.766 us; speedup vs baseline: 1.6405x; 1.0144x over previous
//
#include <hip/hip_runtime.h>
#include <stdint.h>

#define MDIM 16384
#define NDIM 8192
#define KDIM 2048
#define KB2 1024  // packed fp4 row bytes (KDIM/2)
#define EPS32 1.1920928955078125e-07f
#define BM 256
#define BN 256
// K-tile = 128 fp4 elements = 64 bytes per row

using i32x4 = __attribute__((ext_vector_type(4))) int;
using f32x4 = __attribute__((ext_vector_type(4))) float;
using f32x16 = __attribute__((ext_vector_type(16))) float;
typedef __attribute__((address_space(3))) const int8_t* lds_cptr;
typedef __attribute__((address_space(3))) int8_t* lds_ptr;

// fp4 E2M1 nibble: +1.0 = 0x2, -1.0 = 0xA
__device__ __forceinline__ uint32_t nib(float v) { return (v < 0.f) ? 0xAu : 0x2u; }

// ---------------------------------------------------------------------------
// Fused pack (fp4): blocks [0,MDIM) pack A rows + ab[m]; blocks
// [MDIM, MDIM+2048) pack B transposed + atomicMax column bound.
// ---------------------------------------------------------------------------
__global__ __launch_bounds__(256) void k_pack(const float* __restrict__ x,
                                              const float* __restrict__ W,
                                              uint8_t* __restrict__ As,
                                              uint8_t* __restrict__ Bs,
                                              float* __restrict__ ab,
                                              unsigned int* __restrict__ wbu) {
  __shared__ uint8_t sm[64 * 68];
  __shared__ float red[4][64];
  const int t = threadIdx.x;
  if (blockIdx.x < MDIM) {
    const int m = blockIdx.x;
    const float4* row = (const float4*)(x + (size_t)m * KDIM);
    const float4 v0 = row[2 * t];
    const float4 v1 = row[2 * t + 1];
    const uint32_t pk =
        nib(v0.x) | (nib(v0.y) << 4) | (nib(v0.z) << 8) | (nib(v0.w) << 12) |
        (nib(v1.x) << 16) | (nib(v1.y) << 20) | (nib(v1.z) << 24) | (nib(v1.w) << 28);
    ((uint32_t*)(As + (size_t)m * KB2))[t] = pk;
    float mx = fmaxf(fmaxf(fabsf(v0.x), fabsf(v0.y)), fmaxf(fabsf(v0.z), fabsf(v0.w)));
    mx = fmaxf(mx, fmaxf(fmaxf(fabsf(v1.x), fabsf(v1.y)), fmaxf(fabsf(v1.z), fabsf(v1.w))));
#pragma unroll
    for (int o = 32; o > 0; o >>= 1) mx = fmaxf(mx, __shfl_xor(mx, o, 64));
    if ((t & 63) == 0) red[0][t >> 6] = mx;
    __syncthreads();
    if (t == 0)
      ab[m] = fmaxf(fmaxf(red[0][0], red[0][1]), fmaxf(red[0][2], red[0][3])) + EPS32;
  } else {
    const int bid = blockIdx.x - MDIM;
    const int bd = bid & 31;  // 2048/64 d-tiles
    const int bf = bid >> 5;  // 8192/64 f-tiles
    const int d0 = bd * 64, f0 = bf * 64;
    const int fl = t & 63, dq = t >> 6;
    float mx = 0.f;
#pragma unroll
    for (int i = 0; i < 16; ++i) {
      const int dl = i * 4 + dq;
      const float v = W[(size_t)(d0 + dl) * NDIM + f0 + fl];
      sm[fl * 68 + dl] = (uint8_t)nib(v);
      mx = fmaxf(mx, fabsf(v));
    }
    red[dq][fl] = mx;
    __syncthreads();
    if (t < 64) {
      const float r = fmaxf(fmaxf(red[0][t], red[1][t]), fmaxf(red[2][t], red[3][t]));
      atomicMax(&wbu[f0 + t], __float_as_uint(r));
    }
    // writer: 64 f-rows x 32 packed bytes; thread = (row nl, 16-d chunk ch)
    const int nl = t >> 2, ch = t & 3;
    const uint8_t* s = &sm[nl * 68 + ch * 16];
    uint32_t w0 = 0, w1 = 0;
#pragma unroll
    for (int i = 0; i < 4; ++i)
      w0 |= (uint32_t)(s[2 * i] | (s[2 * i + 1] << 4)) << (8 * i);
#pragma unroll
    for (int i = 0; i < 4; ++i)
      w1 |= (uint32_t)(s[8 + 2 * i] | (s[9 + 2 * i] << 4)) << (8 * i);
    *(uint2*)(Bs + (size_t)(f0 + nl) * KB2 + (d0 >> 1) + ch * 8) = make_uint2(w0, w1);
  }
}

// ---------------------------------------------------------------------------
// MX-FP4 sign-GEMM, REG-STAGED (no global_load_lds): 256x256 tile, 8 waves,
// K-tile = 128 elems (64B rows), 4-slot LDS ring, distance-3 prefetch.
// Iter N: {barrier; global_load_dwordx4 tile N+3 -> reg set; vmcnt(4);
// ds_write_b128 tile N+2 (swizzle on write addr); R11 LGK ladder + 16 MFMA}.
// Swizzle: phys16Bslot = logical ^ ((row>>3)&3) (R6-clean, conflicts 0).
// C[m][n] = 0.25 * ab[m] * (wb[n]+eps) * S + bias[n]
// ---------------------------------------------------------------------------
__global__ __launch_bounds__(512, 2) void k_gemm(const uint8_t* __restrict__ As,
                                                 const uint8_t* __restrict__ Bs,
                                                 const float* __restrict__ ab,
                                                 const float* __restrict__ wbf,
                                                 const float* __restrict__ bias,
                                                 float* __restrict__ out) {
  __shared__ int8_t lds[4][32768];  // ring slot: A 16KB | B 16KB
  const int t = threadIdx.x;
  const int lane = t & 63, wid = t >> 6;
  // XCD L2-chunked remap (R5: FETCH 543->197MB). nwg=2048.
  const int bid = blockIdx.x;
  const int xcd = bid & 7;
  const int local = bid >> 3;
  const int bnin = local & 7;
  const int bml = (local >> 3) & 7;
  const int bnc = local >> 6;
  const int bm = xcd * 8 + bml;
  const int bn = bnc * 8 + bnin;
  const size_t m0 = (size_t)bm * BM, n0 = (size_t)bn * BN;
  const int wr = wid >> 2, wc = wid & 3;

  // ----- staging geometry: wave stages A rows wid*32..+31 and B same (4KB).
  // load instr c in {0,1}: 16 rows x 64B; lane L -> row c*16 + (L>>2),
  // col (L&3)*16 (LINEAR global). Write addr carries the swizzle:
  // slot = (L&3) ^ xs(row), xs(row) = (row>>3)&3 = (c*2 + (L>>5)) & 3.
  const int r4 = lane >> 2;
  const int c4 = lane & 3;
  const uint8_t* glA0 = As + (m0 + (size_t)(wid * 32 + r4)) * KB2 + c4 * 16;
  const uint8_t* glA1 = As + (m0 + (size_t)(wid * 32 + 16 + r4)) * KB2 + c4 * 16;
  const uint8_t* glB0 = Bs + (n0 + (size_t)(wid * 32 + r4)) * KB2 + c4 * 16;
  const uint8_t* glB1 = Bs + (n0 + (size_t)(wid * 32 + 16 + r4)) * KB2 + c4 * 16;
  const int xs0 = (lane >> 5) & 1;       // c=0: xs in {0,1}
  const int wsl0 = (c4 ^ xs0) * 16;
  const int wsl1 = (c4 ^ (xs0 ^ 2)) * 16;  // c=1: xs ^= 2
  const int wrowA0 = (wid * 32 + r4) * 64 + wsl0;
  const int wrowA1 = (wid * 32 + 16 + r4) * 64 + wsl1;

  // fragment reads (unchanged, conflict-free): row = l31 (+32 per i),
  // logical slot = kk*2 + h, phys = logical ^ ((l31>>3)&3).
  const int l31 = lane & 31, h = lane >> 5;
  const int xs = (l31 >> 3) & 3;
  const int aoff0 = (wr * 128 + l31) * 64 + ((h ^ xs) * 16);
  const int aoff1 = (wr * 128 + l31) * 64 + (((2 + h) ^ xs) * 16);
  const int boff0 = 16384 + (wc * 64 + l31) * 64 + ((h ^ xs) * 16);
  const int boff1 = 16384 + (wc * 64 + l31) * 64 + (((2 + h) ^ xs) * 16);

  f32x16 acc[4][2];
#pragma unroll
  for (int i = 0; i < 4; ++i)
#pragma unroll
    for (int j = 0; j < 2; ++j) acc[i][j] = (f32x16){0};

  // double-buffered staging regs (E/O): tile u -> set u&1
  i32x4 sE0, sE1, sE2, sE3, sO0, sO1, sO2, sO3;

#define GLOAD(dst, p) \
  asm volatile("global_load_dwordx4 %0, %1, off" : "=v"(dst) : "v"(p))

#define GL4(u, S0, S1, S2, S3)                  \
  do {                                          \
    GLOAD(S0, glA0 + (size_t)(u) * 64);         \
    GLOAD(S1, glA1 + (size_t)(u) * 64);         \
    GLOAD(S2, glB0 + (size_t)(u) * 64);         \
    GLOAD(S3, glB1 + (size_t)(u) * 64);         \
  } while (0)

#define DSW(addr, val, OFF) \
  asm volatile("ds_write_b128 %0, %1 offset:" #OFF :: "v"(addr), "v"(val))

#define WR4(u, S0, S1, S2, S3)                              \
  do {                                                      \
    lds_ptr w0 = (lds_ptr)&lds[(u) & 3][0] + wrowA0;        \
    lds_ptr w1 = (lds_ptr)&lds[(u) & 3][0] + wrowA1;        \
    DSW(w0, S0, 0);                                         \
    DSW(w1, S1, 0);                                         \
    DSW(w0, S2, 16384);                                     \
    DSW(w1, S3, 16384);                                     \
  } while (0)

#define VMW(N)                                              \
  asm volatile("s_waitcnt vmcnt(" #N ")" ::: "memory");     \
  __builtin_amdgcn_sched_barrier(0);

#define DSR(dst, ptr, OFF) \
  asm volatile("ds_read_b128 %0, %1 offset:" #OFF : "=v"(dst) : "v"(ptr))

#define LGK(N)                                              \
  asm volatile("s_waitcnt lgkmcnt(" #N ")" ::: "memory");   \
  __builtin_amdgcn_sched_barrier(0);

#define FRAG(x) __builtin_shufflevector((x), (x), 0, 1, 2, 3, -1, -1, -1, -1)

// swapped operands: D rows = n (b-frag first). fmt 4/4 = fp4, scales = 1.0.
#define SMFMA(D, BF, AF)                                                      \
  D = __builtin_amdgcn_mfma_scale_f32_32x32x64_f8f6f4(                        \
      FRAG(BF), FRAG(AF), D, 4, 4, 0, 0x7F7F7F7F, 0, 0x7F7F7F7F)

#define MP(I, B0, B1, AF) SMFMA(acc[I][0], B0, AF); SMFMA(acc[I][1], B1, AF)

// R11 intra-iter ladder; the 4 ds_writes are oldest in the DS queue so the
// LGK thresholds are unchanged (they drain before the first threshold).
#define LADDER(SLOT)                                                          \
  {                                                                           \
    const int8_t* sb = &lds[(SLOT)][0];                                       \
    lds_cptr pA0 = (lds_cptr)(sb + aoff0);                                    \
    lds_cptr pA1 = (lds_cptr)(sb + aoff1);                                    \
    lds_cptr pB0 = (lds_cptr)(sb + boff0);                                    \
    lds_cptr pB1 = (lds_cptr)(sb + boff1);                                    \
    i32x4 a0, a1, a2, a3, a4, a5, a6, a7, b0, b1, b2, b3;                     \
    DSR(a0, pA0, 0); DSR(b0, pB0, 0); DSR(b1, pB0, 2048);                     \
    DSR(a1, pA0, 2048); DSR(a2, pA0, 4096); DSR(a3, pA0, 6144);               \
    DSR(a4, pA1, 0); DSR(b2, pB1, 0); DSR(b3, pB1, 2048);                     \
    DSR(a5, pA1, 2048); DSR(a6, pA1, 4096); DSR(a7, pA1, 6144);               \
    LGK(9); __builtin_amdgcn_s_setprio(1); MP(0, b0, b1, a0);                 \
    LGK(8); MP(1, b0, b1, a1);                                                \
    LGK(7); MP(2, b0, b1, a2);                                                \
    LGK(6); MP(3, b0, b1, a3);                                                \
    LGK(3); MP(0, b2, b3, a4);                                                \
    LGK(2); MP(1, b2, b3, a5);                                                \
    LGK(1); MP(2, b2, b3, a6);                                                \
    LGK(0); MP(3, b2, b3, a7);                                                \
    __builtin_amdgcn_s_setprio(0);                                            \
  }

// iter TT even: loads(TT+3)->O, writes(TT+2) from E. Odd: swapped.
#define ITER_EVEN(TT, DOLOAD, VMN)                                            \
  {                                                                           \
    __builtin_amdgcn_s_barrier();                                             \
    if (DOLOAD) GL4((TT) + 3, sO0, sO1, sO2, sO3);                            \
    VMW(VMN);                                                                 \
    WR4((TT) + 2, sE0, sE1, sE2, sE3);                                        \
    LADDER((TT) & 3);                                                         \
  }
#define ITER_ODD(TT, DOLOAD, VMN)                                             \
  {                                                                           \
    __builtin_amdgcn_s_barrier();                                             \
    if (DOLOAD) GL4((TT) + 3, sE0, sE1, sE2, sE3);                            \
    VMW(VMN);                                                                 \
    WR4((TT) + 2, sO0, sO1, sO2, sO3);                                        \
    LADDER((TT) & 3);                                                         \
  }

  // prologue: tiles 0,1 -> LDS (slots 0,1); tile 2 -> reg set E
  GL4(0, sE0, sE1, sE2, sE3);
  VMW(0);
  WR4(0, sE0, sE1, sE2, sE3);
  GL4(1, sO0, sO1, sO2, sO3);
  VMW(0);
  WR4(1, sO0, sO1, sO2, sO3);
  asm volatile("s_waitcnt lgkmcnt(0)" ::: "memory");  // writes consumed regs
  GL4(2, sE0, sE1, sE2, sE3);

  for (int tt = 0; tt < 12; tt += 2) {
    ITER_EVEN(tt, 1, 4);
    ITER_ODD(tt + 1, 1, 4);
  }
  ITER_EVEN(12, 1, 4);   // loads tile 15 -> O, writes tile 14 from E
  ITER_ODD(13, 0, 0);    // writes tile 15 from O
  { __builtin_amdgcn_s_barrier(); LADDER(2); }  // tile 14
  { __builtin_amdgcn_s_barrier(); LADDER(3); }  // tile 15

  // epilogue: 32x32 C-map (swapped): m = col = l31, n = (reg&3)+8*(reg>>2)+4*h
#pragma unroll
  for (int i = 0; i < 4; ++i) {
    const size_t m = m0 + wr * 128 + i * 32 + l31;
    const float av = 0.25f * ab[m];
    float* orow = out + m * NDIM;
#pragma unroll
    for (int j = 0; j < 2; ++j) {
#pragma unroll
      for (int q = 0; q < 4; ++q) {
        const size_t nb = n0 + wc * 64 + j * 32 + q * 8 + h * 4;
        const f32x4 wv = *(const f32x4*)&wbf[nb];
        const f32x4 bv = *(const f32x4*)&bias[nb];
        f32x4 o;
        o[0] = av * ((wv[0] + EPS32) * acc[i][j][q * 4 + 0]) + bv[0];
        o[1] = av * ((wv[1] + EPS32) * acc[i][j][q * 4 + 1]) + bv[1];
        o[2] = av * ((wv[2] + EPS32) * acc[i][j][q * 4 + 2]) + bv[2];
        o[3] = av * ((wv[3] + EPS32) * acc[i][j][q * 4 + 3]) + bv[3];
        *(f32x4*)(orow + nb) = o;
      }
    }
  }
#undef ITER_EVEN
#undef ITER_ODD
#undef LADDER
#undef MP
#undef SMFMA
#undef FRAG
#undef LGK
#undef DSR
#undef VMW
#undef WR4
#undef DSW
#undef GL4
#undef GLOAD
}

extern "C" void kernel_launch(void* const* d_in, const int* in_sizes, int n_in,
                              void* d_out, int out_size, void* d_ws, size_t ws_size,
                              hipStream_t stream) {
  const float* x = (const float*)d_in[0];     // (4, 4096, 2048)
  const float* W = (const float*)d_in[1];     // (2048, 8192)
  const float* bias = (const float*)d_in[2];  // (8192,)
  float* out = (float*)d_out;

  char* ws = (char*)d_ws;
  uint8_t* As = (uint8_t*)ws;                                   // 16 MiB fp4
  uint8_t* Bs = (uint8_t*)(ws + (size_t)(16u << 20));           // 8 MiB fp4
  float* ab = (float*)(ws + (size_t)(24u << 20));               // 64 KiB
  float* wb = (float*)(ws + (size_t)(24u << 20) + (1u << 16));  // 32 KiB

  (void)hipMemsetAsync(wb, 0, NDIM * sizeof(float), stream);
  k_pack<<<MDIM + (KDIM / 64) * (NDIM / 64), 256, 0, stream>>>(x, W, As, Bs, ab,
                                                               (unsigned int*)wb);
  k_gemm<<<(MDIM / BM) * (NDIM / BN), 512, 0, stream>>>(As, Bs, ab, wb, bias, out);
}